// Round 5
// baseline (311.621 us; speedup 1.0000x reference)
//
#include <hip/hip_runtime.h>
#include <hip/hip_bf16.h>

#define S_LEN 2048
#define EMB 1024
#define NH 16
#define HD 64
// M = B*S = 4096 rows

typedef __attribute__((ext_vector_type(8))) __bf16 bf16x8;
typedef __attribute__((ext_vector_type(4))) float f32x4;

__device__ inline void gload_lds16(const void* g, void* l) {
    __builtin_amdgcn_global_load_lds(
        (const __attribute__((address_space(1))) unsigned int*)g,
        (__attribute__((address_space(3))) unsigned int*)l, 16, 0, 0);
}

// ---------------------------------------------------------------------------
// Kernel 0: fp32 -> bf16 conversion of x, qkv_w, out_w in ONE launch.
// ---------------------------------------------------------------------------
__global__ __launch_bounds__(256) void cvt_all(
    const float* __restrict__ x, const float* __restrict__ wq,
    const float* __restrict__ wo,
    __hip_bfloat16* __restrict__ xb, __hip_bfloat16* __restrict__ wqb,
    __hip_bfloat16* __restrict__ wob)
{
    const long C_X = (long)4096 * 1024 / 4;       // 1,048,576
    const long C_WQ = (long)3072 * 1024 / 4;      // 786,432
    long c = (long)blockIdx.x * 256 + threadIdx.x;
    const float* in;
    __hip_bfloat16* out;
    if (c < C_X) { in = x; out = xb; }
    else if (c < C_X + C_WQ) { in = wq; out = wqb; c -= C_X; }
    else { in = wo; out = wob; c -= C_X + C_WQ; }
    long i = c * 4;
    float4 v = *(const float4*)(in + i);
    __hip_bfloat16 b0 = __float2bfloat16(v.x);
    __hip_bfloat16 b1 = __float2bfloat16(v.y);
    __hip_bfloat16 b2 = __float2bfloat16(v.z);
    __hip_bfloat16 b3 = __float2bfloat16(v.w);
    ushort4 o = {*(unsigned short*)&b0, *(unsigned short*)&b1,
                 *(unsigned short*)&b2, *(unsigned short*)&b3};
    *(ushort4*)(out + i) = o;
}

// ---------------------------------------------------------------------------
// MFMA GEMM core (m97 structure): C = A @ B^T, 128x128 tile, BK=64, 4 waves.
// EPI=0: quantum epilogue (cos*cos, scatter Q/K/Vt).  EPI=1: fp32 C store.
// Q is pre-scaled by 0.125*log2(e) so attention can use exp2 directly.
// ---------------------------------------------------------------------------
template <int EPI>
__global__ __launch_bounds__(256) void gemm_mfma(
    const __hip_bfloat16* __restrict__ A,   // [M][1024]
    const __hip_bfloat16* __restrict__ B,   // [N][1024]
    const float* __restrict__ qp,           // [64] (EPI=0)
    __hip_bfloat16* __restrict__ Q,         // EPI=0 outputs
    __hip_bfloat16* __restrict__ Kp,
    __hip_bfloat16* __restrict__ Vt,
    float* __restrict__ C)                  // EPI=1 output
{
    const int Kd = 1024;
    __shared__ __align__(16) char Ash[128 * 128];
    __shared__ __align__(16) char Bsh[128 * 128];

    const int t  = threadIdx.x;
    const int w  = t >> 6;
    const int l  = t & 63;
    const int lg = l >> 4, lm = l & 15;
    const int wr = w >> 1, wc = w & 1;
    const int m0 = blockIdx.y * 128;
    const int n0 = blockIdx.x * 128;

    const int r8 = l >> 3;
    const int sb = ((l & 7) * 16) ^ (r8 << 4);
    const char* srcA = (const char*)A + ((long)(m0 + w * 32 + r8) * Kd) * 2 + sb;
    const char* srcB = (const char*)B + ((long)(n0 + w * 32 + r8) * Kd) * 2 + sb;

    f32x4 acc[4][4];
#pragma unroll
    for (int i = 0; i < 4; i++)
#pragma unroll
        for (int j = 0; j < 4; j++) acc[i][j] = (f32x4){0.f, 0.f, 0.f, 0.f};

    for (int kt = 0; kt < Kd * 2; kt += 128) {
#pragma unroll
        for (int j = 0; j < 4; j++) {
            gload_lds16(srcA + (long)j * 8 * Kd * 2 + kt, Ash + (w * 32 + j * 8) * 128);
            gload_lds16(srcB + (long)j * 8 * Kd * 2 + kt, Bsh + (w * 32 + j * 8) * 128);
        }
        __syncthreads();
#pragma unroll
        for (int kk = 0; kk < 2; kk++) {
            bf16x8 af[4], bfr[4];
            const int sw = (lm & 7) << 4;
            const int co = (kk * 64 + lg * 16);
#pragma unroll
            for (int mi = 0; mi < 4; mi++)
                af[mi] = *(const bf16x8*)(Ash + (wr * 64 + mi * 16 + lm) * 128 + (co ^ sw));
#pragma unroll
            for (int ni = 0; ni < 4; ni++)
                bfr[ni] = *(const bf16x8*)(Bsh + (wc * 64 + ni * 16 + lm) * 128 + (co ^ sw));
#pragma unroll
            for (int mi = 0; mi < 4; mi++)
#pragma unroll
                for (int ni = 0; ni < 4; ni++)
                    acc[mi][ni] = __builtin_amdgcn_mfma_f32_16x16x32_bf16(
                        af[mi], bfr[ni], acc[mi][ni], 0, 0, 0);
        }
        __syncthreads();
    }

    if constexpr (EPI == 0) {
        const int which = n0 >> 10;
        float cqp[4];
#pragma unroll
        for (int ni = 0; ni < 4; ni++)
            cqp[ni] = __cosf(qp[(wc * 64 + ni * 16 + lm) & 63]);
#pragma unroll
        for (int mi = 0; mi < 4; mi++) {
#pragma unroll
            for (int r = 0; r < 4; r++) {
                int m = m0 + wr * 64 + mi * 16 + lg * 4 + r;
                int b = m >> 11, s = m & 2047;
#pragma unroll
                for (int ni = 0; ni < 4; ni++) {
                    int n = n0 + wc * 64 + ni * 16 + lm;
                    int d = n & 63;
                    int h = (n & 1023) >> 6;
                    int bh = b * NH + h;
                    float val = __cosf(acc[mi][ni][r]) * cqp[ni];
                    if (which == 0)  // 0.125 * log2(e) folded for exp2 softmax
                        Q[((long)bh * S_LEN + s) * HD + d] = __float2bfloat16(val * 0.180336880f);
                    else if (which == 1)
                        Kp[((long)bh * S_LEN + s) * HD + d] = __float2bfloat16(val);
                    else
                        Vt[((long)bh * HD + d) * S_LEN + s] = __float2bfloat16(val);
                }
            }
        }
    } else {
#pragma unroll
        for (int mi = 0; mi < 4; mi++)
#pragma unroll
            for (int r = 0; r < 4; r++) {
                int m = m0 + wr * 64 + mi * 16 + lg * 4 + r;
#pragma unroll
                for (int ni = 0; ni < 4; ni++) {
                    int n = n0 + wc * 64 + ni * 16 + lm;
                    C[(long)m * 1024 + n] = acc[mi][ni][r];
                }
            }
    }
}

// ---------------------------------------------------------------------------
// Kernel 2: MFMA flash attention, fixed-max softmax, NO K/V LDS staging.
// K/V per head = 256 KB each -> L2-resident; B-operand fragments are 16B-
// contiguous in K [B,H,S,D] and Vt [B,H,D,S], loaded straight to VGPRs
// (Common-mistake #7: don't LDS-stage L2-fitting data). No barriers at all.
// Swapped QK^T: mfma(K_frag, Q_frag) -> S^T with q = lane&15 lane-local,
// so P writes pack to ds_write_b32. P = exp2(S' - 8*log2e); Q pre-scaled
// by 0.125*log2e in the QKV epilogue.
// ---------------------------------------------------------------------------
__global__ __launch_bounds__(256) void attn_mfma(
    const __hip_bfloat16* __restrict__ Q,
    const __hip_bfloat16* __restrict__ K,
    const __hip_bfloat16* __restrict__ Vt,  // [B,H,D,S]
    __hip_bfloat16* __restrict__ O)
{
    __shared__ __align__(16) char Psh[4 * 2048];  // per-wave 16 q-rows x 128B

    const int bh = blockIdx.y;
    const int b  = bh >> 4, h = bh & 15;
    const int q0 = blockIdx.x * 64;
    const int t  = threadIdx.x;
    const int w  = t >> 6;
    const int l  = t & 63;
    const int lg = l >> 4;
    const int lm = l & 15;

    // Q fragment (already scaled by 0.125*log2e): lane holds Q[q=w*16+lm][lg*8..]
    const __hip_bfloat16* Qr =
        Q + ((long)bh * S_LEN + q0 + w * 16 + lm) * HD + lg * 8;
    const bf16x8 qa0 = *(const bf16x8*)(Qr);
    const bf16x8 qa1 = *(const bf16x8*)(Qr + 32);

    const __hip_bfloat16* Kb = K + (long)bh * S_LEN * HD;   // [key][64]
    const __hip_bfloat16* Vb = Vt + (long)bh * HD * S_LEN;  // [d][S]

    f32x4 oacc[4];
#pragma unroll
    for (int n = 0; n < 4; n++) oacc[n] = (f32x4){0.f, 0.f, 0.f, 0.f};
    float lsum = 0.f;

    char* Pw = Psh + w * 2048;
    const int swp = (lm & 7) << 4;
    const float EXPB = 11.54156033f;  // 8 * log2(e)

    for (int kt = 0; kt < S_LEN; kt += 64) {
        // issue ALL global loads first (T14 issue-early): K frags then V frags
        bf16x8 ka0[4], ka1[4], vb0[4], vb1[4];
#pragma unroll
        for (int n0 = 0; n0 < 4; n0++) {
            const __hip_bfloat16* kr = Kb + (long)(kt + n0 * 16 + lm) * HD + lg * 8;
            ka0[n0] = *(const bf16x8*)(kr);
            ka1[n0] = *(const bf16x8*)(kr + 32);
        }
#pragma unroll
        for (int n0 = 0; n0 < 4; n0++) {
            const __hip_bfloat16* vr = Vb + (long)(n0 * 16 + lm) * S_LEN + kt + lg * 8;
            vb0[n0] = *(const bf16x8*)(vr);
            vb1[n0] = *(const bf16x8*)(vr + 32);
        }

        // ---- S^T = K Q^T (swapped operands; same fragments) ----
        f32x4 sacc[4];
#pragma unroll
        for (int n0 = 0; n0 < 4; n0++) {
            f32x4 s = (f32x4){0.f, 0.f, 0.f, 0.f};
            s = __builtin_amdgcn_mfma_f32_16x16x32_bf16(ka0[n0], qa0, s, 0, 0, 0);
            s = __builtin_amdgcn_mfma_f32_16x16x32_bf16(ka1[n0], qa1, s, 0, 0, 0);
            sacc[n0] = s;  // S[q=lm][key = kt + n0*16 + lg*4 + r]
        }

        // ---- fixed-max softmax, lane-local row (q = lm) ----
#pragma unroll
        for (int n0 = 0; n0 < 4; n0++) {
            float p0 = exp2f(sacc[n0][0] - EXPB);
            float p1 = exp2f(sacc[n0][1] - EXPB);
            float p2 = exp2f(sacc[n0][2] - EXPB);
            float p3 = exp2f(sacc[n0][3] - EXPB);
            lsum += (p0 + p1) + (p2 + p3);
            __hip_bfloat16 h0 = __float2bfloat16(p0), h1 = __float2bfloat16(p1);
            __hip_bfloat16 h2 = __float2bfloat16(p2), h3 = __float2bfloat16(p3);
            unsigned w0 = (unsigned)*(unsigned short*)&h0 |
                          ((unsigned)*(unsigned short*)&h1 << 16);
            unsigned w1 = (unsigned)*(unsigned short*)&h2 |
                          ((unsigned)*(unsigned short*)&h3 << 16);
            int kb = (n0 * 16 + lg * 4) * 2;
            *(unsigned*)(Pw + lm * 128 + (kb ^ swp)) = w0;
            *(unsigned*)(Pw + lm * 128 + ((kb + 4) ^ swp)) = w1;
        }

        // ---- O += P V  (A = P from per-wave LDS, B = V^T global frags) ----
#pragma unroll
        for (int kk = 0; kk < 2; kk++) {
            bf16x8 pa = *(const bf16x8*)(Pw + lm * 128 + ((kk * 64 + lg * 16) ^ swp));
#pragma unroll
            for (int n0 = 0; n0 < 4; n0++)
                oacc[n0] = __builtin_amdgcn_mfma_f32_16x16x32_bf16(
                    pa, kk ? vb1[n0] : vb0[n0], oacc[n0], 0, 0, 0);
        }
    }

    // lsum currently: lane holds partial for q=lm over its keys; reduce over lg
    lsum += __shfl_xor(lsum, 16, 64);
    lsum += __shfl_xor(lsum, 32, 64);
    // redistribute: oacc rows are q = lg*4+r; totals live at lanes 0..15 (q=lane)
#pragma unroll
    for (int r = 0; r < 4; r++) {
        float inv = 1.f / __shfl(lsum, lg * 4 + r, 64);
        int qrow = q0 + w * 16 + lg * 4 + r;
        long base = ((long)b * S_LEN + qrow) * EMB + h * HD;
#pragma unroll
        for (int n0 = 0; n0 < 4; n0++)
            O[base + n0 * 16 + lm] = __float2bfloat16(oacc[n0][r] * inv);
    }
}

extern "C" void kernel_launch(void* const* d_in, const int* in_sizes, int n_in,
                              void* d_out, int out_size, void* d_ws, size_t ws_size,
                              hipStream_t stream) {
    const float* x     = (const float*)d_in[0];   // [2,2048,1024]
    const float* qkv_w = (const float*)d_in[1];   // [3072,1024]
    const float* out_w = (const float*)d_in[2];   // [1024,1024]
    const float* qp    = (const float*)d_in[3];   // [64]
    float* out = (float*)d_out;                   // [2,2048,1024] fp32

    const long NELEM = (long)2 * S_LEN * EMB;     // 4,194,304
    __hip_bfloat16* Q   = (__hip_bfloat16*)d_ws;  // [B,H,S,D] (x 0.125*log2e)
    __hip_bfloat16* K   = Q + NELEM;              // [B,H,S,D]
    __hip_bfloat16* Vt  = K + NELEM;              // [B,H,D,S]
    __hip_bfloat16* O   = Vt + NELEM;             // [B,S,E]
    __hip_bfloat16* xb  = O + NELEM;              // [4096][1024]
    __hip_bfloat16* wqb = xb + NELEM;             // [3072][1024]
    __hip_bfloat16* wob = wqb + (long)3072 * 1024;// [1024][1024]

    dim3 blk(256);
    cvt_all<<<dim3(8192), blk, 0, stream>>>(x, qkv_w, out_w, xb, wqb, wob);
    gemm_mfma<0><<<dim3(3072 / 128, 4096 / 128), blk, 0, stream>>>(
        xb, wqb, qp, Q, K, Vt, nullptr);
    attn_mfma<<<dim3(S_LEN / 64, 32), blk, 0, stream>>>(Q, K, Vt, O);
    gemm_mfma<1><<<dim3(1024 / 128, 4096 / 128), blk, 0, stream>>>(
        O, wob, nullptr, nullptr, nullptr, nullptr, out);
}

// Round 6
// 162.391 us; speedup vs baseline: 1.9190x; 1.9190x over previous
//
#include <hip/hip_runtime.h>
#include <hip/hip_bf16.h>

#define S_LEN 2048
#define EMB 1024
#define NH 16
#define HD 64
// M = B*S = 4096 rows

typedef __attribute__((ext_vector_type(8))) __bf16 bf16x8;
typedef __attribute__((ext_vector_type(4))) float f32x4;

__device__ inline void gload_lds16(const void* g, void* l) {
    __builtin_amdgcn_global_load_lds(
        (const __attribute__((address_space(1))) unsigned int*)g,
        (__attribute__((address_space(3))) unsigned int*)l, 16, 0, 0);
}

// ---------------------------------------------------------------------------
// Kernel 0: fp32 -> bf16 conversion of x, qkv_w, out_w in ONE launch.
// ---------------------------------------------------------------------------
__global__ __launch_bounds__(256) void cvt_all(
    const float* __restrict__ x, const float* __restrict__ wq,
    const float* __restrict__ wo,
    __hip_bfloat16* __restrict__ xb, __hip_bfloat16* __restrict__ wqb,
    __hip_bfloat16* __restrict__ wob)
{
    const long C_X = (long)4096 * 1024 / 4;       // 1,048,576
    const long C_WQ = (long)3072 * 1024 / 4;      // 786,432
    long c = (long)blockIdx.x * 256 + threadIdx.x;
    const float* in;
    __hip_bfloat16* out;
    if (c < C_X) { in = x; out = xb; }
    else if (c < C_X + C_WQ) { in = wq; out = wqb; c -= C_X; }
    else { in = wo; out = wob; c -= C_X + C_WQ; }
    long i = c * 4;
    float4 v = *(const float4*)(in + i);
    __hip_bfloat16 b0 = __float2bfloat16(v.x);
    __hip_bfloat16 b1 = __float2bfloat16(v.y);
    __hip_bfloat16 b2 = __float2bfloat16(v.z);
    __hip_bfloat16 b3 = __float2bfloat16(v.w);
    ushort4 o = {*(unsigned short*)&b0, *(unsigned short*)&b1,
                 *(unsigned short*)&b2, *(unsigned short*)&b3};
    *(ushort4*)(out + i) = o;
}

// ---------------------------------------------------------------------------
// MFMA GEMM core (m97 structure): C = A @ B^T, 128x128 tile, BK=64, 4 waves.
// EPI=0: quantum epilogue (cos*cos, scatter Q/K/Vt).  EPI=1: fp32 C store.
// Q is pre-scaled by 0.125*log2(e) so attention can use exp2 directly.
// ---------------------------------------------------------------------------
template <int EPI>
__global__ __launch_bounds__(256) void gemm_mfma(
    const __hip_bfloat16* __restrict__ A,   // [M][1024]
    const __hip_bfloat16* __restrict__ B,   // [N][1024]
    const float* __restrict__ qp,           // [64] (EPI=0)
    __hip_bfloat16* __restrict__ Q,         // EPI=0 outputs
    __hip_bfloat16* __restrict__ Kp,
    __hip_bfloat16* __restrict__ Vt,
    float* __restrict__ C)                  // EPI=1 output
{
    const int Kd = 1024;
    __shared__ __align__(16) char Ash[128 * 128];
    __shared__ __align__(16) char Bsh[128 * 128];

    const int t  = threadIdx.x;
    const int w  = t >> 6;
    const int l  = t & 63;
    const int lg = l >> 4, lm = l & 15;
    const int wr = w >> 1, wc = w & 1;
    const int m0 = blockIdx.y * 128;
    const int n0 = blockIdx.x * 128;

    const int r8 = l >> 3;
    const int sb = ((l & 7) * 16) ^ (r8 << 4);
    const char* srcA = (const char*)A + ((long)(m0 + w * 32 + r8) * Kd) * 2 + sb;
    const char* srcB = (const char*)B + ((long)(n0 + w * 32 + r8) * Kd) * 2 + sb;

    f32x4 acc[4][4];
#pragma unroll
    for (int i = 0; i < 4; i++)
#pragma unroll
        for (int j = 0; j < 4; j++) acc[i][j] = (f32x4){0.f, 0.f, 0.f, 0.f};

    for (int kt = 0; kt < Kd * 2; kt += 128) {
#pragma unroll
        for (int j = 0; j < 4; j++) {
            gload_lds16(srcA + (long)j * 8 * Kd * 2 + kt, Ash + (w * 32 + j * 8) * 128);
            gload_lds16(srcB + (long)j * 8 * Kd * 2 + kt, Bsh + (w * 32 + j * 8) * 128);
        }
        __syncthreads();
#pragma unroll
        for (int kk = 0; kk < 2; kk++) {
            bf16x8 af[4], bfr[4];
            const int sw = (lm & 7) << 4;
            const int co = (kk * 64 + lg * 16);
#pragma unroll
            for (int mi = 0; mi < 4; mi++)
                af[mi] = *(const bf16x8*)(Ash + (wr * 64 + mi * 16 + lm) * 128 + (co ^ sw));
#pragma unroll
            for (int ni = 0; ni < 4; ni++)
                bfr[ni] = *(const bf16x8*)(Bsh + (wc * 64 + ni * 16 + lm) * 128 + (co ^ sw));
#pragma unroll
            for (int mi = 0; mi < 4; mi++)
#pragma unroll
                for (int ni = 0; ni < 4; ni++)
                    acc[mi][ni] = __builtin_amdgcn_mfma_f32_16x16x32_bf16(
                        af[mi], bfr[ni], acc[mi][ni], 0, 0, 0);
        }
        __syncthreads();
    }

    if constexpr (EPI == 0) {
        const int which = n0 >> 10;
        float cqp[4];
#pragma unroll
        for (int ni = 0; ni < 4; ni++)
            cqp[ni] = __cosf(qp[(wc * 64 + ni * 16 + lm) & 63]);
#pragma unroll
        for (int mi = 0; mi < 4; mi++) {
#pragma unroll
            for (int r = 0; r < 4; r++) {
                int m = m0 + wr * 64 + mi * 16 + lg * 4 + r;
                int b = m >> 11, s = m & 2047;
#pragma unroll
                for (int ni = 0; ni < 4; ni++) {
                    int n = n0 + wc * 64 + ni * 16 + lm;
                    int d = n & 63;
                    int h = (n & 1023) >> 6;
                    int bh = b * NH + h;
                    float val = __cosf(acc[mi][ni][r]) * cqp[ni];
                    if (which == 0)  // 0.125 * log2(e) folded for exp2 softmax
                        Q[((long)bh * S_LEN + s) * HD + d] = __float2bfloat16(val * 0.180336880f);
                    else if (which == 1)
                        Kp[((long)bh * S_LEN + s) * HD + d] = __float2bfloat16(val);
                    else
                        Vt[((long)bh * HD + d) * S_LEN + s] = __float2bfloat16(val);
                }
            }
        }
    } else {
#pragma unroll
        for (int mi = 0; mi < 4; mi++)
#pragma unroll
            for (int r = 0; r < 4; r++) {
                int m = m0 + wr * 64 + mi * 16 + lg * 4 + r;
#pragma unroll
                for (int ni = 0; ni < 4; ni++) {
                    int n = n0 + wc * 64 + ni * 16 + lm;
                    C[(long)m * 1024 + n] = acc[mi][ni][r];
                }
            }
    }
}

// ---------------------------------------------------------------------------
// Kernel 2: MFMA flash attention. Round-4 DMA-staged structure (K/V in
// swizzled LDS via global_load_lds, proven 78us) + round-5 numerics
// (swapped QK^T -> lane-local softmax rows, exp2 with log2e pre-folded,
// packed b32 P stores) + QBLK=128: each wave owns 32 q-rows as TWO
// 16-row fragments, so the 16 K/V ds_read_b128 per tile are shared by
// 2x the MFMA work (32 MFMA vs 20 LDS reads per wave-tile).
// Fixed-max softmax (|S'| <= 8*log2e provably). No K/V re-read per wave.
// ---------------------------------------------------------------------------
__global__ __launch_bounds__(256) void attn_mfma(
    const __hip_bfloat16* __restrict__ Q,
    const __hip_bfloat16* __restrict__ K,
    const __hip_bfloat16* __restrict__ Vt,  // [B,H,D,S]
    __hip_bfloat16* __restrict__ O)
{
    __shared__ __align__(16) char Ksh[64 * 128];   // 64 keys x 64 d (swz)
    __shared__ __align__(16) char Vsh[64 * 128];   // 64 d x 64 keys (swz)
    __shared__ __align__(16) char Psh[4 * 4096];   // per-wave 32 q x 128B (swz)

    const int bh = blockIdx.y;
    const int b  = bh >> 4, h = bh & 15;
    const int q0 = blockIdx.x * 128;
    const int t  = threadIdx.x;
    const int w  = t >> 6;
    const int l  = t & 63;
    const int lg = l >> 4;
    const int lm = l & 15;

    // Q fragments (pre-scaled by 0.125*log2e): f=0,1 -> rows w*32 + f*16 + lm
    bf16x8 qa[2][2];
#pragma unroll
    for (int f = 0; f < 2; f++) {
        const __hip_bfloat16* Qr =
            Q + ((long)bh * S_LEN + q0 + w * 32 + f * 16 + lm) * HD + lg * 8;
        qa[f][0] = *(const bf16x8*)(Qr);
        qa[f][1] = *(const bf16x8*)(Qr + 32);
    }

    f32x4 oacc[2][4];
#pragma unroll
    for (int f = 0; f < 2; f++)
#pragma unroll
        for (int n = 0; n < 4; n++) oacc[f][n] = (f32x4){0.f, 0.f, 0.f, 0.f};
    float lsum[2] = {0.f, 0.f};

    char* Pw = Psh + w * 4096;
    const int swp = (lm & 7) << 4;
    const float EXPB = 11.54156033f;  // 8 * log2(e)

    const char* Kgb = (const char*)(K + (long)bh * S_LEN * HD);
    const char* Vgb = (const char*)(Vt + (long)bh * HD * S_LEN);

    // DMA staging: lane l covers LDS row rr = w*8 + (l>>3) (+32 chunk 2),
    // 16B col (l&7). Linear LDS dest; source byte pre-swizzled by ((rr&7)<<4).
    const int swb = ((l & 7) * 16) ^ (((l >> 3) & 7) << 4);
    const int row0 = w * 8 + (l >> 3);
    const char* Ksrc  = Kgb + (long)row0 * 128 + swb;                  // +kt*128
    const char* Vsrc0 = Vgb + (long)row0 * (S_LEN * 2) + swb;          // +kt*2
    const char* Vsrc1 = Vgb + (long)(row0 + 32) * (S_LEN * 2) + swb;   // +kt*2

    for (int kt = 0; kt < S_LEN; kt += 64) {
        __syncthreads();  // previous tile's LDS reads done
        gload_lds16(Ksrc + (long)kt * 128, Ksh + w * 1024);
        gload_lds16(Ksrc + (long)(kt + 32) * 128, Ksh + w * 1024 + 4096);
        gload_lds16(Vsrc0 + (long)kt * 2, Vsh + w * 1024);
        gload_lds16(Vsrc1 + (long)kt * 2, Vsh + w * 1024 + 4096);
        __syncthreads();  // DMA drained + all staged

        // ---- S^T = K Q^T. A-frag = K row (shared across f), B-frag = qa[f].
        // Lane lm reads K[key = n0*16+lm][d-halves] from swizzled LDS.
        f32x4 sacc[2][4];
#pragma unroll
        for (int n0 = 0; n0 < 4; n0++) {
            int row = n0 * 16 + lm;
            int swr = (row & 7) << 4;
            bf16x8 k0 = *(const bf16x8*)(Ksh + row * 128 + ((lg * 16) ^ swr));
            bf16x8 k1 = *(const bf16x8*)(Ksh + row * 128 + ((64 + lg * 16) ^ swr));
#pragma unroll
            for (int f = 0; f < 2; f++) {
                f32x4 s = (f32x4){0.f, 0.f, 0.f, 0.f};
                s = __builtin_amdgcn_mfma_f32_16x16x32_bf16(k0, qa[f][0], s, 0, 0, 0);
                s = __builtin_amdgcn_mfma_f32_16x16x32_bf16(k1, qa[f][1], s, 0, 0, 0);
                sacc[f][n0] = s;  // S[q=lm (group f)][key = kt + n0*16 + lg*4 + r]
            }
        }

        // ---- fixed-max softmax, lane-local rows; pack P to bf16 pairs ----
#pragma unroll
        for (int f = 0; f < 2; f++) {
#pragma unroll
            for (int n0 = 0; n0 < 4; n0++) {
                float p0 = exp2f(sacc[f][n0][0] - EXPB);
                float p1 = exp2f(sacc[f][n0][1] - EXPB);
                float p2 = exp2f(sacc[f][n0][2] - EXPB);
                float p3 = exp2f(sacc[f][n0][3] - EXPB);
                lsum[f] += (p0 + p1) + (p2 + p3);
                __hip_bfloat16 h0 = __float2bfloat16(p0), h1 = __float2bfloat16(p1);
                __hip_bfloat16 h2 = __float2bfloat16(p2), h3 = __float2bfloat16(p3);
                unsigned w0 = (unsigned)*(unsigned short*)&h0 |
                              ((unsigned)*(unsigned short*)&h1 << 16);
                unsigned w1 = (unsigned)*(unsigned short*)&h2 |
                              ((unsigned)*(unsigned short*)&h3 << 16);
                int kb = (n0 * 16 + lg * 4) * 2;
                char* Prow = Pw + (f * 16 + lm) * 128;
                *(unsigned*)(Prow + (kb ^ swp)) = w0;
                *(unsigned*)(Prow + ((kb + 4) ^ swp)) = w1;
            }
        }

        // ---- O += P V. vb (shared across f) from swizzled LDS V^T tile ----
#pragma unroll
        for (int kk = 0; kk < 2; kk++) {
            bf16x8 pa[2];
#pragma unroll
            for (int f = 0; f < 2; f++)
                pa[f] = *(const bf16x8*)(
                    Pw + (f * 16 + lm) * 128 + ((kk * 64 + lg * 16) ^ swp));
#pragma unroll
            for (int n0 = 0; n0 < 4; n0++) {
                int row = n0 * 16 + lm;  // d index
                bf16x8 vb = *(const bf16x8*)(
                    Vsh + row * 128 + ((kk * 64 + lg * 16) ^ ((row & 7) << 4)));
#pragma unroll
                for (int f = 0; f < 2; f++)
                    oacc[f][n0] = __builtin_amdgcn_mfma_f32_16x16x32_bf16(
                        pa[f], vb, oacc[f][n0], 0, 0, 0);
            }
        }
    }

    // lsum[f]: lane holds partial for q=lm over its 16 keys/tile; sum over lg
#pragma unroll
    for (int f = 0; f < 2; f++) {
        lsum[f] += __shfl_xor(lsum[f], 16, 64);
        lsum[f] += __shfl_xor(lsum[f], 32, 64);
    }
    // oacc rows are q = f*16 + lg*4 + r; totals live at lane lm == q&15
#pragma unroll
    for (int f = 0; f < 2; f++) {
#pragma unroll
        for (int r = 0; r < 4; r++) {
            float inv = 1.f / __shfl(lsum[f], lg * 4 + r, 64);
            int qrow = q0 + w * 32 + f * 16 + lg * 4 + r;
            long base = ((long)b * S_LEN + qrow) * EMB + h * HD;
#pragma unroll
            for (int n0 = 0; n0 < 4; n0++)
                O[base + n0 * 16 + lm] = __float2bfloat16(oacc[f][n0][r] * inv);
        }
    }
}

extern "C" void kernel_launch(void* const* d_in, const int* in_sizes, int n_in,
                              void* d_out, int out_size, void* d_ws, size_t ws_size,
                              hipStream_t stream) {
    const float* x     = (const float*)d_in[0];   // [2,2048,1024]
    const float* qkv_w = (const float*)d_in[1];   // [3072,1024]
    const float* out_w = (const float*)d_in[2];   // [1024,1024]
    const float* qp    = (const float*)d_in[3];   // [64]
    float* out = (float*)d_out;                   // [2,2048,1024] fp32

    const long NELEM = (long)2 * S_LEN * EMB;     // 4,194,304
    __hip_bfloat16* Q   = (__hip_bfloat16*)d_ws;  // [B,H,S,D] (x 0.125*log2e)
    __hip_bfloat16* K   = Q + NELEM;              // [B,H,S,D]
    __hip_bfloat16* Vt  = K + NELEM;              // [B,H,D,S]
    __hip_bfloat16* O   = Vt + NELEM;             // [B,S,E]
    __hip_bfloat16* xb  = O + NELEM;              // [4096][1024]
    __hip_bfloat16* wqb = xb + NELEM;             // [3072][1024]
    __hip_bfloat16* wob = wqb + (long)3072 * 1024;// [1024][1024]

    dim3 blk(256);
    cvt_all<<<dim3(8192), blk, 0, stream>>>(x, qkv_w, out_w, xb, wqb, wob);
    gemm_mfma<0><<<dim3(3072 / 128, 4096 / 128), blk, 0, stream>>>(
        xb, wqb, qp, Q, K, Vt, nullptr);
    attn_mfma<<<dim3(S_LEN / 128, 32), blk, 0, stream>>>(Q, K, Vt, O);
    gemm_mfma<1><<<dim3(1024 / 128, 4096 / 128), blk, 0, stream>>>(
        O, wob, nullptr, nullptr, nullptr, nullptr, out);
}

// Round 7
// 155.014 us; speedup vs baseline: 2.0103x; 1.0476x over previous
//
#include <hip/hip_runtime.h>
#include <hip/hip_bf16.h>

#define S_LEN 2048
#define EMB 1024
#define NH 16
#define HD 64
// M = B*S = 4096 rows

typedef __attribute__((ext_vector_type(8))) __bf16 bf16x8;
typedef __attribute__((ext_vector_type(4))) float f32x4;

__device__ inline void gload_lds16(const void* g, void* l) {
    __builtin_amdgcn_global_load_lds(
        (const __attribute__((address_space(1))) unsigned int*)g,
        (__attribute__((address_space(3))) unsigned int*)l, 16, 0, 0);
}

// ---------------------------------------------------------------------------
// Kernel 0: fp32 -> bf16 conversion of x, qkv_w, out_w in ONE launch.
// ---------------------------------------------------------------------------
__global__ __launch_bounds__(256) void cvt_all(
    const float* __restrict__ x, const float* __restrict__ wq,
    const float* __restrict__ wo,
    __hip_bfloat16* __restrict__ xb, __hip_bfloat16* __restrict__ wqb,
    __hip_bfloat16* __restrict__ wob)
{
    const long C_X = (long)4096 * 1024 / 4;       // 1,048,576
    const long C_WQ = (long)3072 * 1024 / 4;      // 786,432
    long c = (long)blockIdx.x * 256 + threadIdx.x;
    const float* in;
    __hip_bfloat16* out;
    if (c < C_X) { in = x; out = xb; }
    else if (c < C_X + C_WQ) { in = wq; out = wqb; c -= C_X; }
    else { in = wo; out = wob; c -= C_X + C_WQ; }
    long i = c * 4;
    float4 v = *(const float4*)(in + i);
    __hip_bfloat16 b0 = __float2bfloat16(v.x);
    __hip_bfloat16 b1 = __float2bfloat16(v.y);
    __hip_bfloat16 b2 = __float2bfloat16(v.z);
    __hip_bfloat16 b3 = __float2bfloat16(v.w);
    ushort4 o = {*(unsigned short*)&b0, *(unsigned short*)&b1,
                 *(unsigned short*)&b2, *(unsigned short*)&b3};
    *(ushort4*)(out + i) = o;
}

// ---------------------------------------------------------------------------
// MFMA GEMM core (m97 structure): C = A @ B^T, 128x128 tile, BK=64, 4 waves.
// EPI=0: quantum epilogue (cos*cos, scatter Q/K/Vt).  EPI=1: fp32 C store.
// Q is pre-scaled by 0.125*log2(e) so attention can use exp2 directly.
// ---------------------------------------------------------------------------
template <int EPI>
__global__ __launch_bounds__(256) void gemm_mfma(
    const __hip_bfloat16* __restrict__ A,   // [M][1024]
    const __hip_bfloat16* __restrict__ B,   // [N][1024]
    const float* __restrict__ qp,           // [64] (EPI=0)
    __hip_bfloat16* __restrict__ Q,         // EPI=0 outputs
    __hip_bfloat16* __restrict__ Kp,
    __hip_bfloat16* __restrict__ Vt,
    float* __restrict__ C)                  // EPI=1 output
{
    const int Kd = 1024;
    __shared__ __align__(16) char Ash[128 * 128];
    __shared__ __align__(16) char Bsh[128 * 128];

    const int t  = threadIdx.x;
    const int w  = t >> 6;
    const int l  = t & 63;
    const int lg = l >> 4, lm = l & 15;
    const int wr = w >> 1, wc = w & 1;
    const int m0 = blockIdx.y * 128;
    const int n0 = blockIdx.x * 128;

    const int r8 = l >> 3;
    const int sb = ((l & 7) * 16) ^ (r8 << 4);
    const char* srcA = (const char*)A + ((long)(m0 + w * 32 + r8) * Kd) * 2 + sb;
    const char* srcB = (const char*)B + ((long)(n0 + w * 32 + r8) * Kd) * 2 + sb;

    f32x4 acc[4][4];
#pragma unroll
    for (int i = 0; i < 4; i++)
#pragma unroll
        for (int j = 0; j < 4; j++) acc[i][j] = (f32x4){0.f, 0.f, 0.f, 0.f};

    for (int kt = 0; kt < Kd * 2; kt += 128) {
#pragma unroll
        for (int j = 0; j < 4; j++) {
            gload_lds16(srcA + (long)j * 8 * Kd * 2 + kt, Ash + (w * 32 + j * 8) * 128);
            gload_lds16(srcB + (long)j * 8 * Kd * 2 + kt, Bsh + (w * 32 + j * 8) * 128);
        }
        __syncthreads();
#pragma unroll
        for (int kk = 0; kk < 2; kk++) {
            bf16x8 af[4], bfr[4];
            const int sw = (lm & 7) << 4;
            const int co = (kk * 64 + lg * 16);
#pragma unroll
            for (int mi = 0; mi < 4; mi++)
                af[mi] = *(const bf16x8*)(Ash + (wr * 64 + mi * 16 + lm) * 128 + (co ^ sw));
#pragma unroll
            for (int ni = 0; ni < 4; ni++)
                bfr[ni] = *(const bf16x8*)(Bsh + (wc * 64 + ni * 16 + lm) * 128 + (co ^ sw));
#pragma unroll
            for (int mi = 0; mi < 4; mi++)
#pragma unroll
                for (int ni = 0; ni < 4; ni++)
                    acc[mi][ni] = __builtin_amdgcn_mfma_f32_16x16x32_bf16(
                        af[mi], bfr[ni], acc[mi][ni], 0, 0, 0);
        }
        __syncthreads();
    }

    if constexpr (EPI == 0) {
        const int which = n0 >> 10;
        float cqp[4];
#pragma unroll
        for (int ni = 0; ni < 4; ni++)
            cqp[ni] = __cosf(qp[(wc * 64 + ni * 16 + lm) & 63]);
#pragma unroll
        for (int mi = 0; mi < 4; mi++) {
#pragma unroll
            for (int r = 0; r < 4; r++) {
                int m = m0 + wr * 64 + mi * 16 + lg * 4 + r;
                int b = m >> 11, s = m & 2047;
#pragma unroll
                for (int ni = 0; ni < 4; ni++) {
                    int n = n0 + wc * 64 + ni * 16 + lm;
                    int d = n & 63;
                    int h = (n & 1023) >> 6;
                    int bh = b * NH + h;
                    float val = __cosf(acc[mi][ni][r]) * cqp[ni];
                    if (which == 0)  // 0.125 * log2(e) folded for exp2 softmax
                        Q[((long)bh * S_LEN + s) * HD + d] = __float2bfloat16(val * 0.180336880f);
                    else if (which == 1)
                        Kp[((long)bh * S_LEN + s) * HD + d] = __float2bfloat16(val);
                    else
                        Vt[((long)bh * HD + d) * S_LEN + s] = __float2bfloat16(val);
                }
            }
        }
    } else {
#pragma unroll
        for (int mi = 0; mi < 4; mi++)
#pragma unroll
            for (int r = 0; r < 4; r++) {
                int m = m0 + wr * 64 + mi * 16 + lg * 4 + r;
#pragma unroll
                for (int ni = 0; ni < 4; ni++) {
                    int n = n0 + wc * 64 + ni * 16 + lm;
                    C[(long)m * 1024 + n] = acc[mi][ni][r];
                }
            }
    }
}

// ---------------------------------------------------------------------------
// Kernel 2: MFMA flash attention. QBLK=64 (1024 blocks, 4/CU — round-4's
// proven parallelism) + double-buffered K/V DMA staging with ONE barrier
// per tile: barrier(cur ready) -> issue DMA(next->alt) -> compute(cur).
// The compiler's vmcnt(0)-before-barrier then drains a DMA that had a full
// compute phase to land. Numerics: swapped QK^T (lane-local softmax rows),
// fixed-max exp2 (log2e pre-folded into Q), P packed to ds_write_b64.
// setprio(1) around MFMA clusters (T5, attn-proven).
// ---------------------------------------------------------------------------
__global__ __launch_bounds__(256) void attn_mfma(
    const __hip_bfloat16* __restrict__ Q,
    const __hip_bfloat16* __restrict__ K,
    const __hip_bfloat16* __restrict__ Vt,  // [B,H,D,S]
    __hip_bfloat16* __restrict__ O)
{
    __shared__ __align__(16) char Ksh[2][64 * 128];  // 64 keys x 64 d (swz)
    __shared__ __align__(16) char Vsh[2][64 * 128];  // 64 d x 64 keys (swz)
    __shared__ __align__(16) char Psh[4 * 2048];     // per-wave 16 q x 128B (swz)

    const int bh = blockIdx.y;
    const int b  = bh >> 4, h = bh & 15;
    const int q0 = blockIdx.x * 64;
    const int t  = threadIdx.x;
    const int w  = t >> 6;
    const int l  = t & 63;
    const int lg = l >> 4;
    const int lm = l & 15;

    // Q fragment (pre-scaled by 0.125*log2e): lane holds Q[q=w*16+lm][lg*8..]
    const __hip_bfloat16* Qr =
        Q + ((long)bh * S_LEN + q0 + w * 16 + lm) * HD + lg * 8;
    const bf16x8 qa0 = *(const bf16x8*)(Qr);
    const bf16x8 qa1 = *(const bf16x8*)(Qr + 32);

    f32x4 oacc[4];
#pragma unroll
    for (int n = 0; n < 4; n++) oacc[n] = (f32x4){0.f, 0.f, 0.f, 0.f};
    float lsum = 0.f;

    char* Pw = Psh + w * 2048;
    const int swp = (lm & 7) << 4;
    const float EXPB = 11.54156033f;  // 8 * log2(e)

    const char* Kgb = (const char*)(K + (long)bh * S_LEN * HD);
    const char* Vgb = (const char*)(Vt + (long)bh * HD * S_LEN);

    // DMA staging: lane l covers LDS row rr = w*8 + (l>>3) (+32 chunk 2),
    // 16B col (l&7). Linear LDS dest; source byte pre-swizzled by ((rr&7)<<4).
    const int swb = ((l & 7) * 16) ^ (((l >> 3) & 7) << 4);
    const int row0 = w * 8 + (l >> 3);
    const char* Ksrc  = Kgb + (long)row0 * 128 + swb;                  // +kt*128
    const char* Vsrc0 = Vgb + (long)row0 * (S_LEN * 2) + swb;          // +kt*2
    const char* Vsrc1 = Vgb + (long)(row0 + 32) * (S_LEN * 2) + swb;   // +kt*2

    // prologue: stage tile 0 into buffer 0
    gload_lds16(Ksrc, Ksh[0] + w * 1024);
    gload_lds16(Ksrc + 32 * 128, Ksh[0] + w * 1024 + 4096);
    gload_lds16(Vsrc0, Vsh[0] + w * 1024);
    gload_lds16(Vsrc1, Vsh[0] + w * 1024 + 4096);

    int cur = 0;
    for (int kt = 0; kt < S_LEN; kt += 64) {
        __syncthreads();  // vmcnt(0) drained -> buf[cur] staged; alt reads done

        if (kt + 64 < S_LEN) {  // stage next tile into alternate buffer
            int nk = kt + 64;
            gload_lds16(Ksrc + (long)nk * 128, Ksh[cur ^ 1] + w * 1024);
            gload_lds16(Ksrc + (long)(nk + 32) * 128, Ksh[cur ^ 1] + w * 1024 + 4096);
            gload_lds16(Vsrc0 + (long)nk * 2, Vsh[cur ^ 1] + w * 1024);
            gload_lds16(Vsrc1 + (long)nk * 2, Vsh[cur ^ 1] + w * 1024 + 4096);
        }

        const char* Kc = Ksh[cur];
        const char* Vc = Vsh[cur];

        // ---- S^T = K Q^T (A-frag = K row, B-frag = Q row; q = lm lane-local)
        f32x4 sacc[4];
        __builtin_amdgcn_s_setprio(1);
#pragma unroll
        for (int n0 = 0; n0 < 4; n0++) {
            int row = n0 * 16 + lm;
            int swr = (row & 7) << 4;
            bf16x8 k0 = *(const bf16x8*)(Kc + row * 128 + ((lg * 16) ^ swr));
            bf16x8 k1 = *(const bf16x8*)(Kc + row * 128 + ((64 + lg * 16) ^ swr));
            f32x4 s = (f32x4){0.f, 0.f, 0.f, 0.f};
            s = __builtin_amdgcn_mfma_f32_16x16x32_bf16(k0, qa0, s, 0, 0, 0);
            s = __builtin_amdgcn_mfma_f32_16x16x32_bf16(k1, qa1, s, 0, 0, 0);
            sacc[n0] = s;  // S[q=lm][key = kt + n0*16 + lg*4 + r]
        }
        __builtin_amdgcn_s_setprio(0);

        // ---- fixed-max softmax, lane-local row q=lm; pack 4 bf16 -> b64 ----
#pragma unroll
        for (int n0 = 0; n0 < 4; n0++) {
            float p0 = exp2f(sacc[n0][0] - EXPB);
            float p1 = exp2f(sacc[n0][1] - EXPB);
            float p2 = exp2f(sacc[n0][2] - EXPB);
            float p3 = exp2f(sacc[n0][3] - EXPB);
            lsum += (p0 + p1) + (p2 + p3);
            __hip_bfloat16 h0 = __float2bfloat16(p0), h1 = __float2bfloat16(p1);
            __hip_bfloat16 h2 = __float2bfloat16(p2), h3 = __float2bfloat16(p3);
            uint2 pw;
            pw.x = (unsigned)*(unsigned short*)&h0 |
                   ((unsigned)*(unsigned short*)&h1 << 16);
            pw.y = (unsigned)*(unsigned short*)&h2 |
                   ((unsigned)*(unsigned short*)&h3 << 16);
            int kb = (n0 * 16 + lg * 4) * 2;     // multiple of 8 -> b64 aligned
            *(uint2*)(Pw + lm * 128 + (kb ^ swp)) = pw;
        }

        // ---- O += P V  (A = P from per-wave LDS, B = V^T swizzled tile) ----
        __builtin_amdgcn_s_setprio(1);
#pragma unroll
        for (int kk = 0; kk < 2; kk++) {
            bf16x8 pa = *(const bf16x8*)(Pw + lm * 128 + ((kk * 64 + lg * 16) ^ swp));
#pragma unroll
            for (int n0 = 0; n0 < 4; n0++) {
                int row = n0 * 16 + lm;  // d index
                bf16x8 vb = *(const bf16x8*)(
                    Vc + row * 128 + ((kk * 64 + lg * 16) ^ ((row & 7) << 4)));
                oacc[n0] = __builtin_amdgcn_mfma_f32_16x16x32_bf16(
                    pa, vb, oacc[n0], 0, 0, 0);
            }
        }
        __builtin_amdgcn_s_setprio(0);
        cur ^= 1;
    }

    // lsum: lane holds partial for q=lm over its 16 keys/tile; sum over lg
    lsum += __shfl_xor(lsum, 16, 64);
    lsum += __shfl_xor(lsum, 32, 64);
    // oacc rows are q = lg*4 + r; totals live at lane lm == q
#pragma unroll
    for (int r = 0; r < 4; r++) {
        float inv = 1.f / __shfl(lsum, lg * 4 + r, 64);
        int qrow = q0 + w * 16 + lg * 4 + r;
        long base = ((long)b * S_LEN + qrow) * EMB + h * HD;
#pragma unroll
        for (int n0 = 0; n0 < 4; n0++)
            O[base + n0 * 16 + lm] = __float2bfloat16(oacc[n0][r] * inv);
    }
}

extern "C" void kernel_launch(void* const* d_in, const int* in_sizes, int n_in,
                              void* d_out, int out_size, void* d_ws, size_t ws_size,
                              hipStream_t stream) {
    const float* x     = (const float*)d_in[0];   // [2,2048,1024]
    const float* qkv_w = (const float*)d_in[1];   // [3072,1024]
    const float* out_w = (const float*)d_in[2];   // [1024,1024]
    const float* qp    = (const float*)d_in[3];   // [64]
    float* out = (float*)d_out;                   // [2,2048,1024] fp32

    const long NELEM = (long)2 * S_LEN * EMB;     // 4,194,304
    __hip_bfloat16* Q   = (__hip_bfloat16*)d_ws;  // [B,H,S,D] (x 0.125*log2e)
    __hip_bfloat16* K   = Q + NELEM;              // [B,H,S,D]
    __hip_bfloat16* Vt  = K + NELEM;              // [B,H,D,S]
    __hip_bfloat16* O   = Vt + NELEM;             // [B,S,E]
    __hip_bfloat16* xb  = O + NELEM;              // [4096][1024]
    __hip_bfloat16* wqb = xb + NELEM;             // [3072][1024]
    __hip_bfloat16* wob = wqb + (long)3072 * 1024;// [1024][1024]

    dim3 blk(256);
    cvt_all<<<dim3(8192), blk, 0, stream>>>(x, qkv_w, out_w, xb, wqb, wob);
    gemm_mfma<0><<<dim3(3072 / 128, 4096 / 128), blk, 0, stream>>>(
        xb, wqb, qp, Q, K, Vt, nullptr);
    attn_mfma<<<dim3(S_LEN / 64, 32), blk, 0, stream>>>(Q, K, Vt, O);
    gemm_mfma<1><<<dim3(1024 / 128, 4096 / 128), blk, 0, stream>>>(
        O, wob, nullptr, nullptr, nullptr, nullptr, out);
}